// Round 6
// baseline (11803.577 us; speedup 1.0000x reference)
//
#include <hip/hip_runtime.h>
#include <math.h>

#define BB 512     // batch
#define HH 1024    // hidden
#define OO 512     // output
#define KC 1536    // O + H
#define G4H 4096   // 4*H
#define TT 256     // out_len

typedef _Float16 half8 __attribute__((ext_vector_type(8)));
typedef float f32x4 __attribute__((ext_vector_type(4)));

// async global->LDS DMA, 16B/lane (logits-kernel staging — proven path)
__device__ __forceinline__ void dma16(const void* g, void* l) {
    __builtin_amdgcn_global_load_lds(
        (const __attribute__((address_space(1))) void*)g,
        (__attribute__((address_space(3))) void*)l, 16, 0, 0);
}

// ---------------------------------------------------------------------------
// Prep: Wcat f16 gate-interleaved (row-major [p][KC]), 32-granular permutation
// (round-0 proven): p -> jr = p&31, g = (p>>5)&3, jt = p>>7, n = g*HH+jt*32+jr.
// Wout16 row-major [O][H].
// ---------------------------------------------------------------------------
__global__ __launch_bounds__(256) void conv_wcat(
    const float* __restrict__ W_ih, const float* __restrict__ W_hh,
    _Float16* __restrict__ Wcat)
{
    int k = blockIdx.x * 256 + threadIdx.x;
    int p = blockIdx.y;
    int g = (p >> 5) & 3, jt = p >> 7, jr = p & 31;
    int n = g * HH + jt * 32 + jr;
    float v = (k < OO) ? W_ih[(size_t)n * OO + k] : W_hh[(size_t)n * HH + (k - OO)];
    Wcat[(size_t)p * KC + k] = (_Float16)v;
}

__global__ __launch_bounds__(256) void conv_wout(
    const float* __restrict__ W_out, _Float16* __restrict__ Wout16)
{
    int k = blockIdx.x * 256 + threadIdx.x;  // 0..1023
    int o = blockIdx.y;                      // 0..511
    Wout16[(size_t)o * HH + k] = (_Float16)W_out[(size_t)o * HH + k];
}

__global__ __launch_bounds__(256) void prep_misc(
    const float* __restrict__ b_ih, const float* __restrict__ b_hh,
    const float* __restrict__ h0, const float* __restrict__ c0,
    float* __restrict__ bias_p, _Float16* __restrict__ hb0, float* __restrict__ cst)
{
    int idx0 = blockIdx.x * blockDim.x + threadIdx.x;
    int stride = gridDim.x * blockDim.x;
    for (int p = idx0; p < G4H; p += stride) {
        int g = (p >> 5) & 3, jt = p >> 7, jr = p & 31;
        int n = g * HH + jt * 32 + jr;
        bias_p[p] = b_ih[n] + b_hh[n];
    }
    for (int i = idx0; i < BB * HH; i += stride) {
        hb0[i] = (_Float16)h0[i];
        cst[i] = c0[i];
    }
}

// ---------------------------------------------------------------------------
// gates_sf: round-0 proven gates kernel (64b x 128p tile, BK=128, register-
// prefetch double buffering, grid (32,8)=256 blocks) PLUS fused softmax of the
// PREVIOUS step's logits:
//   - prologue: per-row (m, 1/s) via the exact softmax reduce order of the old
//     softmax_kernel; pt==0 blocks also write the f32 out slice for step t-1.
//   - A-staging for k0 < OO synthesizes x on the fly:
//     x = (f16)(expf(logit - m) * inv)  — identical arithmetic to the old
//     store->load path.
//   x is never materialized in memory; h ping-pongs between two [B][H] f16
//   buffers. Saves one kernel launch per step (3 -> 2).
// ---------------------------------------------------------------------------
__global__ __launch_bounds__(256) void gates_sf(
    const float* __restrict__ logits,     // [B][O] logits of step t-1 (unused if first)
    const _Float16* __restrict__ h_in,    // [B][H]
    _Float16* __restrict__ h_out,         // [B][H]
    float* __restrict__ cst,              // [B][H]
    const _Float16* __restrict__ Wcat,    // [4096][KC] permuted
    const float* __restrict__ bias_p,     // [4096] permuted
    float* __restrict__ out_slice,        // out slice for step t-1 (unused if first)
    int first)
{
    const int pt = blockIdx.x;
    const int p0 = pt * 128, b0 = blockIdx.y * 64;
    const int tid = threadIdx.x;
    const int l = tid & 63, w = tid >> 6;
    const int wm = w & 1, wn = w >> 1;    // 2(b) x 2(p) waves
    const int l15 = l & 15, l4 = l >> 4;

    __shared__ __align__(16) char smem[49664];
    _Float16* Af = (_Float16*)smem;              // [64][128] (16 KB), swizzled
    _Float16* Bf = (_Float16*)(smem + 16384);    // [128][128] (32 KB)
    float* sm_m   = (float*)(smem + 49152);      // [64]
    float* sm_inv = (float*)(smem + 49408);      // [64]

    // ---- prologue: softmax stats (+ out write by pt==0 blocks) -------------
    if (!first) {
        #pragma unroll 1
        for (int rr = 0; rr < 16; ++rr) {
            int bl = w * 16 + rr;                 // batch-local 0..63
            const float* lr = &logits[(size_t)(b0 + bl) * OO];
            float v[8];
            *(float4*)&v[0] = *(const float4*)&lr[l * 8];
            *(float4*)&v[4] = *(const float4*)&lr[l * 8 + 4];

            float m = v[0];
            #pragma unroll
            for (int u = 1; u < 8; ++u) m = fmaxf(m, v[u]);
            #pragma unroll
            for (int off = 1; off < 64; off <<= 1) m = fmaxf(m, __shfl_xor(m, off, 64));

            float s = 0.f;
            #pragma unroll
            for (int u = 0; u < 8; ++u) { v[u] = expf(v[u] - m); s += v[u]; }
            #pragma unroll
            for (int off = 1; off < 64; off <<= 1) s += __shfl_xor(s, off, 64);

            float inv = 1.f / s;
            if (l == 0) { sm_m[bl] = m; sm_inv[bl] = inv; }
            if (pt == 0) {
                float y[8];
                #pragma unroll
                for (int u = 0; u < 8; ++u) y[u] = v[u] * inv;
                float* os = &out_slice[(size_t)(b0 + bl) * OO];
                *(float4*)&os[l * 8]     = *(const float4*)&y[0];
                *(float4*)&os[l * 8 + 4] = *(const float4*)&y[4];
            }
        }
    }
    __syncthreads();   // sm_m/sm_inv visible to all waves

    f32x4 acc[2][4];
    #pragma unroll
    for (int fm = 0; fm < 2; ++fm)
        #pragma unroll
        for (int fn = 0; fn < 4; ++fn)
            acc[fm][fn] = (f32x4){0.f, 0.f, 0.f, 0.f};

    half8 ra[4], rb[8];    // staging registers

    auto load_regs = [&](int k0) {
        if (k0 < OO) {
            // x-part: synthesize softmax values on the fly
            #pragma unroll
            for (int j = 0; j < 4; ++j) {
                int row = (w * 4 + j) * 4 + l4;
                int c = l15 ^ (row & 7);
                const float* lp = &logits[(size_t)(b0 + row) * OO + k0 + c * 8];
                float lv[8];
                *(float4*)&lv[0] = *(const float4*)lp;
                *(float4*)&lv[4] = *(const float4*)(lp + 4);
                float m = sm_m[row], inv = sm_inv[row];
                #pragma unroll
                for (int e = 0; e < 8; ++e)
                    ra[j][e] = (_Float16)(expf(lv[e] - m) * inv);
            }
        } else {
            #pragma unroll
            for (int j = 0; j < 4; ++j) {
                int row = (w * 4 + j) * 4 + l4;
                int c = l15 ^ (row & 7);
                ra[j] = *(const half8*)&h_in[(size_t)(b0 + row) * HH + (k0 - OO) + c * 8];
            }
        }
        #pragma unroll
        for (int j = 0; j < 8; ++j) {          // B: weights, cached
            int row = (w * 8 + j) * 4 + l4;
            int c = l15 ^ (row & 7);
            rb[j] = *(const half8*)&Wcat[(size_t)(p0 + row) * KC + k0 + c * 8];
        }
    };
    auto store_lds = [&]() {
        #pragma unroll
        for (int j = 0; j < 4; ++j)
            *(half8*)&Af[(size_t)(w * 4 + j) * 512 + l * 8] = ra[j];
        #pragma unroll
        for (int j = 0; j < 8; ++j)
            *(half8*)&Bf[(size_t)(w * 8 + j) * 512 + l * 8] = rb[j];
    };

    const int it0 = first ? 4 : 0;     // x contributes 0 at t=0 (x_0 = 0)
    load_regs(it0 * 128);
    #pragma unroll 1
    for (int it = it0; it < KC / 128; ++it) {
        __syncthreads();                       // prior compute done reading LDS
        store_lds();                           // (waits vmcnt on ra/rb here)
        __syncthreads();                       // staging visible to all waves
        if (it + 1 < KC / 128) load_regs((it + 1) * 128);   // prefetch

        #pragma unroll
        for (int ks = 0; ks < 4; ++ks) {
            int cc = (ks * 4 + l4) ^ (l15 & 7);    // swizzled chunk slot
            half8 af[2], bfr[4];
            #pragma unroll
            for (int fm = 0; fm < 2; ++fm) {
                int R = wm * 32 + fm * 16 + l15;
                af[fm] = *(const half8*)&Af[R * 128 + cc * 8];
            }
            #pragma unroll
            for (int fn = 0; fn < 4; ++fn) {
                int S = wn * 64 + fn * 16 + l15;
                bfr[fn] = *(const half8*)&Bf[S * 128 + cc * 8];
            }
            #pragma unroll
            for (int fm = 0; fm < 2; ++fm)
                #pragma unroll
                for (int fn = 0; fn < 4; ++fn)
                    acc[fm][fn] = __builtin_amdgcn_mfma_f32_16x16x32_f16(
                        af[fm], bfr[fn], acc[fm][fn], 0, 0, 0);
        }
    }
    __syncthreads();

    // exchange preactivations through LDS (overlay), stride 133 fp32
    float* exch = (float*)smem;   // [64][133]
    #pragma unroll
    for (int fm = 0; fm < 2; ++fm)
        #pragma unroll
        for (int fn = 0; fn < 4; ++fn)
            #pragma unroll
            for (int r = 0; r < 4; ++r) {
                int row = wm * 32 + fm * 16 + l4 * 4 + r;   // batch-local
                int col = wn * 64 + fn * 16 + l15;          // p-local
                exch[row * 133 + col] = acc[fm][fn][r];
            }
    __syncthreads();

    // cell update: thread -> batch-local bl = tid>>2, jr = (tid&3)*8 + u
    int bl = tid >> 2;
    int b = b0 + bl;
    int jbase = (tid & 3) * 8;
    float cv[8], hv[8], cold[8];
    *(float4*)&cold[0] = *(const float4*)&cst[(size_t)b * HH + pt * 32 + jbase];
    *(float4*)&cold[4] = *(const float4*)&cst[(size_t)b * HH + pt * 32 + jbase + 4];
    #pragma unroll
    for (int u = 0; u < 8; ++u) {
        int jr = jbase + u;
        float gi = exch[bl * 133 +      jr] + bias_p[p0 +      jr];
        float gf = exch[bl * 133 + 32 + jr] + bias_p[p0 + 32 + jr];
        float gg = exch[bl * 133 + 64 + jr] + bias_p[p0 + 64 + jr];
        float go = exch[bl * 133 + 96 + jr] + bias_p[p0 + 96 + jr];
        float iv = 1.f / (1.f + expf(-gi));
        float fv = 1.f / (1.f + expf(-gf));
        float gv = tanhf(gg);
        float ov = 1.f / (1.f + expf(-go));
        float cnew = fv * cold[u] + iv * gv;
        cv[u] = cnew;
        hv[u] = ov * tanhf(cnew);
    }
    *(float4*)&cst[(size_t)b * HH + pt * 32 + jbase]     = *(const float4*)&cv[0];
    *(float4*)&cst[(size_t)b * HH + pt * 32 + jbase + 4] = *(const float4*)&cv[4];
    half8 hh;
    #pragma unroll
    for (int u = 0; u < 8; ++u) hh[u] = (_Float16)hv[u];
    *(half8*)&h_out[(size_t)b * HH + pt * 32 + jbase] = hh;
}

// ---------------------------------------------------------------------------
// logits: PROVEN kernel; A-source is the h buffer [B][H]. 32b x 32o tiles,
// grid (16,16)=256 blocks, 128 threads (2 waves), BK=128, DMA staging+swizzle.
// ---------------------------------------------------------------------------
__global__ __launch_bounds__(128) void logits_mfma(
    const _Float16* __restrict__ hb,      // [B][H]
    const _Float16* __restrict__ Wout16,  // [O][H]
    const float* __restrict__ b_out,
    float* __restrict__ logits)           // [B][O]
{
    const int o0 = blockIdx.x * 32, b0 = blockIdx.y * 32;
    const int tid = threadIdx.x;
    const int l = tid & 63, w = tid >> 6;  // 2 waves: batch halves
    const int l15 = l & 15, l4 = l >> 4, lo3 = l & 7;

    __shared__ __align__(16) _Float16 Ah[32 * 128];
    __shared__ __align__(16) _Float16 Bo[32 * 128];

    f32x4 acc[2];
    acc[0] = (f32x4){0.f, 0.f, 0.f, 0.f};
    acc[1] = (f32x4){0.f, 0.f, 0.f, 0.f};

    for (int k0 = 0; k0 < HH; k0 += 128) {
        #pragma unroll
        for (int j = 0; j < 4; ++j) {       // A: 32 rows (batches)
            int row = (w * 4 + j) * 4 + l4;
            int c = l15 ^ (row & 7);
            dma16(&hb[(size_t)(b0 + row) * HH + k0 + c * 8],
                  &Ah[(size_t)(w * 4 + j) * 512]);
        }
        #pragma unroll
        for (int j = 0; j < 4; ++j) {       // B: 32 rows (o)
            int row = (w * 4 + j) * 4 + l4;
            int c = l15 ^ (row & 7);
            dma16(&Wout16[(size_t)(o0 + row) * HH + k0 + c * 8],
                  &Bo[(size_t)(w * 4 + j) * 512]);
        }
        __syncthreads();
        #pragma unroll
        for (int ks = 0; ks < 4; ++ks) {
            int cc = (ks * 4 + l4) ^ lo3;
            int R = w * 16 + l15;
            half8 a = *(const half8*)&Ah[R * 128 + cc * 8];
            #pragma unroll
            for (int fn = 0; fn < 2; ++fn) {
                int S = fn * 16 + l15;
                half8 bq = *(const half8*)&Bo[S * 128 + cc * 8];
                acc[fn] = __builtin_amdgcn_mfma_f32_16x16x32_f16(a, bq, acc[fn], 0, 0, 0);
            }
        }
        __syncthreads();
    }
    #pragma unroll
    for (int fn = 0; fn < 2; ++fn)
        #pragma unroll
        for (int r = 0; r < 4; ++r) {
            int row = b0 + w * 16 + l4 * 4 + r;
            int col = o0 + fn * 16 + l15;
            logits[(size_t)row * OO + col] = acc[fn][r] + b_out[col];
        }
}

// ---------------------------------------------------------------------------
// softmax_out: final slice only (slice 0, from logits_{TT-1}); identical math
// to the proven softmax_kernel, minus the x write (x_{TT} never needed).
// ---------------------------------------------------------------------------
__global__ __launch_bounds__(256) void softmax_out(
    const float* __restrict__ logits, float* __restrict__ out_slice)
{
    const int w = threadIdx.x >> 6, l = threadIdx.x & 63;
    const int b = blockIdx.x * 4 + w;
    float v[8];
    *(float4*)&v[0] = *(const float4*)&logits[(size_t)b * OO + l * 8];
    *(float4*)&v[4] = *(const float4*)&logits[(size_t)b * OO + l * 8 + 4];

    float m = v[0];
    #pragma unroll
    for (int u = 1; u < 8; ++u) m = fmaxf(m, v[u]);
    #pragma unroll
    for (int off = 1; off < 64; off <<= 1) m = fmaxf(m, __shfl_xor(m, off, 64));

    float s = 0.f;
    #pragma unroll
    for (int u = 0; u < 8; ++u) { v[u] = expf(v[u] - m); s += v[u]; }
    #pragma unroll
    for (int off = 1; off < 64; off <<= 1) s += __shfl_xor(s, off, 64);

    float inv = 1.f / s;
    float y[8];
    #pragma unroll
    for (int u = 0; u < 8; ++u) y[u] = v[u] * inv;
    *(float4*)&out_slice[(size_t)b * OO + l * 8]     = *(const float4*)&y[0];
    *(float4*)&out_slice[(size_t)b * OO + l * 8 + 4] = *(const float4*)&y[4];
}

// ---------------------------------------------------------------------------
extern "C" void kernel_launch(void* const* d_in, const int* in_sizes, int n_in,
                              void* d_out, int out_size, void* d_ws, size_t ws_size,
                              hipStream_t stream)
{
    const float* h0    = (const float*)d_in[0];
    const float* c0    = (const float*)d_in[1];
    const float* W_ih  = (const float*)d_in[2];
    const float* W_hh  = (const float*)d_in[3];
    const float* b_ih  = (const float*)d_in[4];
    const float* b_hh  = (const float*)d_in[5];
    const float* W_out = (const float*)d_in[6];
    const float* b_out = (const float*)d_in[7];
    float* out = (float*)d_out;

    char* wsb = (char*)d_ws;
    _Float16* Wcat   = (_Float16*)wsb;                 wsb += (size_t)G4H * KC * 2;
    _Float16* Wout16 = (_Float16*)wsb;                 wsb += (size_t)OO * HH * 2;
    float*    bias_p = (float*)wsb;                    wsb += (size_t)G4H * 4;
    _Float16* hb0    = (_Float16*)wsb;                 wsb += (size_t)BB * HH * 2;
    _Float16* hb1    = (_Float16*)wsb;                 wsb += (size_t)BB * HH * 2;
    float*    cst    = (float*)wsb;                    wsb += (size_t)BB * HH * 4;
    float*    logits = (float*)wsb;                    wsb += (size_t)BB * OO * 4;

    conv_wcat<<<dim3(KC / 256, G4H), 256, 0, stream>>>(W_ih, W_hh, Wcat);
    conv_wout<<<dim3(HH / 256, OO), 256, 0, stream>>>(W_out, Wout16);
    prep_misc<<<512, 256, 0, stream>>>(b_ih, b_hh, h0, c0, bias_p, hb0, cst);

    for (int t = 0; t < TT; ++t) {
        _Float16* hin  = (t & 1) ? hb1 : hb0;
        _Float16* hout = (t & 1) ? hb0 : hb1;
        // gates_sf at step t consumes softmax(logits_{t-1}) inline and writes
        // the out slice for step t-1 (slice TT-t). t=0: x=0, no prologue;
        // pass a valid (unused) pointer instead of out+TT*BB*OO.
        float* oslice = (t == 0) ? out : out + (size_t)(TT - t) * BB * OO;
        gates_sf<<<dim3(32, 8), 256, 0, stream>>>(
            logits, hin, hout, cst, Wcat, bias_p, oslice, (t == 0) ? 1 : 0);
        logits_mfma<<<dim3(16, 16), 128, 0, stream>>>(hout, Wout16, b_out, logits);
    }
    // final softmax: logits_{TT-1} -> out slice 0
    softmax_out<<<128, 256, 0, stream>>>(logits, out);
}

// Round 7
// 7473.318 us; speedup vs baseline: 1.5794x; 1.5794x over previous
//
#include <hip/hip_runtime.h>
#include <math.h>

#define BB 512     // batch
#define HH 1024    // hidden
#define OO 512     // output
#define KC 1536    // O + H
#define G4H 4096   // 4*H
#define TT 256     // out_len

typedef _Float16 half8 __attribute__((ext_vector_type(8)));
typedef float f32x4 __attribute__((ext_vector_type(4)));

// async global->LDS DMA, 16B/lane (logits-kernel staging — proven path)
__device__ __forceinline__ void dma16(const void* g, void* l) {
    __builtin_amdgcn_global_load_lds(
        (const __attribute__((address_space(1))) void*)g,
        (__attribute__((address_space(3))) void*)l, 16, 0, 0);
}

// ---------------------------------------------------------------------------
// Prep: Wcat f16 gate-interleaved (row-major [p][KC]), 32-granular permutation
// (round-0 proven): p -> jr = p&31, g = (p>>5)&3, jt = p>>7, n = g*HH+jt*32+jr.
// Wout16 row-major [O][H].
// ---------------------------------------------------------------------------
__global__ __launch_bounds__(256) void conv_wcat(
    const float* __restrict__ W_ih, const float* __restrict__ W_hh,
    _Float16* __restrict__ Wcat)
{
    int k = blockIdx.x * 256 + threadIdx.x;
    int p = blockIdx.y;
    int g = (p >> 5) & 3, jt = p >> 7, jr = p & 31;
    int n = g * HH + jt * 32 + jr;
    float v = (k < OO) ? W_ih[(size_t)n * OO + k] : W_hh[(size_t)n * HH + (k - OO)];
    Wcat[(size_t)p * KC + k] = (_Float16)v;
}

__global__ __launch_bounds__(256) void conv_wout(
    const float* __restrict__ W_out, _Float16* __restrict__ Wout16)
{
    int k = blockIdx.x * 256 + threadIdx.x;  // 0..1023
    int o = blockIdx.y;                      // 0..511
    Wout16[(size_t)o * HH + k] = (_Float16)W_out[(size_t)o * HH + k];
}

__global__ __launch_bounds__(256) void prep_misc(
    const float* __restrict__ b_ih, const float* __restrict__ b_hh,
    const float* __restrict__ h0, const float* __restrict__ c0,
    float* __restrict__ bias_p, _Float16* __restrict__ hb0, float* __restrict__ cst)
{
    int idx0 = blockIdx.x * blockDim.x + threadIdx.x;
    int stride = gridDim.x * blockDim.x;
    for (int p = idx0; p < G4H; p += stride) {
        int g = (p >> 5) & 3, jt = p >> 7, jr = p & 31;
        int n = g * HH + jt * 32 + jr;
        bias_p[p] = b_ih[n] + b_hh[n];
    }
    for (int i = idx0; i < BB * HH; i += stride) {
        hb0[i] = (_Float16)h0[i];
        cst[i] = c0[i];
    }
}

// ---------------------------------------------------------------------------
// gates_sf2: round-0 proven gates GEMM (64b x 128p tile, BK=128, register-
// prefetch double buffering, grid (32,8)=256 blocks) + NO-REDUNDANCY softmax
// consumption:
//   - ebuf[b][o] = exp(logit) (f32) and Spart[b][16] (partial row sums) were
//     produced by logits_exp of the previous step.
//   - prologue: tid<64 computes inv[row] = 1/sum(Spart[row][0..16)) (cheap);
//     all threads then write this block's 2 rows of the f32 out slice
//     (y = e * inv) — spread across all 256 blocks, ~8 KB each.
//   - A-staging for k0 < OO synthesizes x = (f16)(e * inv): one mul per
//     element, NO exp (this was R6's 32x-redundant mistake).
// ---------------------------------------------------------------------------
__global__ __launch_bounds__(256) void gates_sf2(
    const float* __restrict__ ebuf,       // [B][O] exp(logits) of step t-1
    const float* __restrict__ Spart,      // [B][16] partial sums
    const _Float16* __restrict__ h_in,    // [B][H]
    _Float16* __restrict__ h_out,         // [B][H]
    float* __restrict__ cst,              // [B][H]
    const _Float16* __restrict__ Wcat,    // [4096][KC] permuted
    const float* __restrict__ bias_p,     // [4096] permuted
    float* __restrict__ out_slice,        // out slice for step t-1
    int first)
{
    const int pt = blockIdx.x;
    const int p0 = pt * 128, b0 = blockIdx.y * 64;
    const int tid = threadIdx.x;
    const int l = tid & 63, w = tid >> 6;
    const int wm = w & 1, wn = w >> 1;    // 2(b) x 2(p) waves
    const int l15 = l & 15, l4 = l >> 4;

    __shared__ __align__(16) char smem[49408];
    _Float16* Af = (_Float16*)smem;              // [64][128] (16 KB), swizzled
    _Float16* Bf = (_Float16*)(smem + 16384);    // [128][128] (32 KB)
    float* sm_inv = (float*)(smem + 49152);      // [64]

    // ---- prologue: 1/rowsum + this block's 2 out rows ----------------------
    if (!first) {
        if (tid < 64) {
            const float* sp = &Spart[(size_t)(b0 + tid) * 16];
            float s = 0.f;
            #pragma unroll
            for (int u = 0; u < 16; ++u) s += sp[u];
            sm_inv[tid] = 1.f / s;
        }
        __syncthreads();
        // out rows: batch-local bl = pt*2 + (tid>>7), col = (tid&127)*4
        int bl = pt * 2 + (tid >> 7);
        int col = (tid & 127) * 4;
        float inv = sm_inv[bl];
        float4 e4 = *(const float4*)&ebuf[(size_t)(b0 + bl) * OO + col];
        float4 y4 = {e4.x * inv, e4.y * inv, e4.z * inv, e4.w * inv};
        *(float4*)&out_slice[(size_t)(b0 + bl) * OO + col] = y4;
    }
    __syncthreads();   // sm_inv visible (and harmless at t=0)

    f32x4 acc[2][4];
    #pragma unroll
    for (int fm = 0; fm < 2; ++fm)
        #pragma unroll
        for (int fn = 0; fn < 4; ++fn)
            acc[fm][fn] = (f32x4){0.f, 0.f, 0.f, 0.f};

    half8 ra[4], rb[8];    // staging registers

    auto load_regs = [&](int k0) {
        if (k0 < OO) {
            // x-part: x = (f16)(e * inv) — one mul per element, no exp
            #pragma unroll
            for (int j = 0; j < 4; ++j) {
                int row = (w * 4 + j) * 4 + l4;
                int c = l15 ^ (row & 7);
                const float* lp = &ebuf[(size_t)(b0 + row) * OO + k0 + c * 8];
                float lv[8];
                *(float4*)&lv[0] = *(const float4*)lp;
                *(float4*)&lv[4] = *(const float4*)(lp + 4);
                float inv = sm_inv[row];
                #pragma unroll
                for (int e = 0; e < 8; ++e)
                    ra[j][e] = (_Float16)(lv[e] * inv);
            }
        } else {
            #pragma unroll
            for (int j = 0; j < 4; ++j) {
                int row = (w * 4 + j) * 4 + l4;
                int c = l15 ^ (row & 7);
                ra[j] = *(const half8*)&h_in[(size_t)(b0 + row) * HH + (k0 - OO) + c * 8];
            }
        }
        #pragma unroll
        for (int j = 0; j < 8; ++j) {          // B: weights, cached
            int row = (w * 8 + j) * 4 + l4;
            int c = l15 ^ (row & 7);
            rb[j] = *(const half8*)&Wcat[(size_t)(p0 + row) * KC + k0 + c * 8];
        }
    };
    auto store_lds = [&]() {
        #pragma unroll
        for (int j = 0; j < 4; ++j)
            *(half8*)&Af[(size_t)(w * 4 + j) * 512 + l * 8] = ra[j];
        #pragma unroll
        for (int j = 0; j < 8; ++j)
            *(half8*)&Bf[(size_t)(w * 8 + j) * 512 + l * 8] = rb[j];
    };

    const int it0 = first ? 4 : 0;     // x contributes 0 at t=0 (x_0 = 0)
    load_regs(it0 * 128);
    #pragma unroll 1
    for (int it = it0; it < KC / 128; ++it) {
        __syncthreads();                       // prior compute done reading LDS
        store_lds();                           // (waits vmcnt on ra/rb here)
        __syncthreads();                       // staging visible to all waves
        if (it + 1 < KC / 128) load_regs((it + 1) * 128);   // prefetch

        #pragma unroll
        for (int ks = 0; ks < 4; ++ks) {
            int cc = (ks * 4 + l4) ^ (l15 & 7);    // swizzled chunk slot
            half8 af[2], bfr[4];
            #pragma unroll
            for (int fm = 0; fm < 2; ++fm) {
                int R = wm * 32 + fm * 16 + l15;
                af[fm] = *(const half8*)&Af[R * 128 + cc * 8];
            }
            #pragma unroll
            for (int fn = 0; fn < 4; ++fn) {
                int S = wn * 64 + fn * 16 + l15;
                bfr[fn] = *(const half8*)&Bf[S * 128 + cc * 8];
            }
            #pragma unroll
            for (int fm = 0; fm < 2; ++fm)
                #pragma unroll
                for (int fn = 0; fn < 4; ++fn)
                    acc[fm][fn] = __builtin_amdgcn_mfma_f32_16x16x32_f16(
                        af[fm], bfr[fn], acc[fm][fn], 0, 0, 0);
        }
    }
    __syncthreads();

    // exchange preactivations through LDS (overlay), stride 133 fp32
    float* exch = (float*)smem;   // [64][133]
    #pragma unroll
    for (int fm = 0; fm < 2; ++fm)
        #pragma unroll
        for (int fn = 0; fn < 4; ++fn)
            #pragma unroll
            for (int r = 0; r < 4; ++r) {
                int row = wm * 32 + fm * 16 + l4 * 4 + r;   // batch-local
                int col = wn * 64 + fn * 16 + l15;          // p-local
                exch[row * 133 + col] = acc[fm][fn][r];
            }
    __syncthreads();

    // cell update: thread -> batch-local bl = tid>>2, jr = (tid&3)*8 + u
    int bl = tid >> 2;
    int b = b0 + bl;
    int jbase = (tid & 3) * 8;
    float cv[8], hv[8], cold[8];
    *(float4*)&cold[0] = *(const float4*)&cst[(size_t)b * HH + pt * 32 + jbase];
    *(float4*)&cold[4] = *(const float4*)&cst[(size_t)b * HH + pt * 32 + jbase + 4];
    #pragma unroll
    for (int u = 0; u < 8; ++u) {
        int jr = jbase + u;
        float gi = exch[bl * 133 +      jr] + bias_p[p0 +      jr];
        float gf = exch[bl * 133 + 32 + jr] + bias_p[p0 + 32 + jr];
        float gg = exch[bl * 133 + 64 + jr] + bias_p[p0 + 64 + jr];
        float go = exch[bl * 133 + 96 + jr] + bias_p[p0 + 96 + jr];
        float iv = 1.f / (1.f + expf(-gi));
        float fv = 1.f / (1.f + expf(-gf));
        float gv = tanhf(gg);
        float ov = 1.f / (1.f + expf(-go));
        float cnew = fv * cold[u] + iv * gv;
        cv[u] = cnew;
        hv[u] = ov * tanhf(cnew);
    }
    *(float4*)&cst[(size_t)b * HH + pt * 32 + jbase]     = *(const float4*)&cv[0];
    *(float4*)&cst[(size_t)b * HH + pt * 32 + jbase + 4] = *(const float4*)&cv[4];
    half8 hh;
    #pragma unroll
    for (int u = 0; u < 8; ++u) hh[u] = (_Float16)hv[u];
    *(half8*)&h_out[(size_t)b * HH + pt * 32 + jbase] = hh;
}

// ---------------------------------------------------------------------------
// logits_exp: PROVEN logits GEMM (32b x 32o tiles, grid (16,16)=256 blocks,
// 128 threads, BK=128, DMA staging + swizzle); epilogue applies
// e = expf(acc + b_out) ONCE per element, stores e (f32) and the per-block
// partial row sums Spart[b][ot] (4 shfls, no atomics, full coverage).
// ---------------------------------------------------------------------------
__global__ __launch_bounds__(128) void logits_exp(
    const _Float16* __restrict__ hb,      // [B][H]
    const _Float16* __restrict__ Wout16,  // [O][H]
    const float* __restrict__ b_out,
    float* __restrict__ ebuf,             // [B][O] exp(logits)
    float* __restrict__ Spart)            // [B][16]
{
    const int ot = blockIdx.x;
    const int o0 = ot * 32, b0 = blockIdx.y * 32;
    const int tid = threadIdx.x;
    const int l = tid & 63, w = tid >> 6;  // 2 waves: batch halves
    const int l15 = l & 15, l4 = l >> 4, lo3 = l & 7;

    __shared__ __align__(16) _Float16 Ah[32 * 128];
    __shared__ __align__(16) _Float16 Bo[32 * 128];

    f32x4 acc[2];
    acc[0] = (f32x4){0.f, 0.f, 0.f, 0.f};
    acc[1] = (f32x4){0.f, 0.f, 0.f, 0.f};

    for (int k0 = 0; k0 < HH; k0 += 128) {
        #pragma unroll
        for (int j = 0; j < 4; ++j) {       // A: 32 rows (batches)
            int row = (w * 4 + j) * 4 + l4;
            int c = l15 ^ (row & 7);
            dma16(&hb[(size_t)(b0 + row) * HH + k0 + c * 8],
                  &Ah[(size_t)(w * 4 + j) * 512]);
        }
        #pragma unroll
        for (int j = 0; j < 4; ++j) {       // B: 32 rows (o)
            int row = (w * 4 + j) * 4 + l4;
            int c = l15 ^ (row & 7);
            dma16(&Wout16[(size_t)(o0 + row) * HH + k0 + c * 8],
                  &Bo[(size_t)(w * 4 + j) * 512]);
        }
        __syncthreads();
        #pragma unroll
        for (int ks = 0; ks < 4; ++ks) {
            int cc = (ks * 4 + l4) ^ lo3;
            int R = w * 16 + l15;
            half8 a = *(const half8*)&Ah[R * 128 + cc * 8];
            #pragma unroll
            for (int fn = 0; fn < 2; ++fn) {
                int S = fn * 16 + l15;
                half8 bq = *(const half8*)&Bo[S * 128 + cc * 8];
                acc[fn] = __builtin_amdgcn_mfma_f32_16x16x32_f16(a, bq, acc[fn], 0, 0, 0);
            }
        }
        __syncthreads();
    }
    // epilogue: e = exp(logit), store + partial row sums
    float ps[4] = {0.f, 0.f, 0.f, 0.f};
    #pragma unroll
    for (int fn = 0; fn < 2; ++fn)
        #pragma unroll
        for (int r = 0; r < 4; ++r) {
            int row = b0 + w * 16 + l4 * 4 + r;
            int col = o0 + fn * 16 + l15;
            float e = expf(acc[fn][r] + b_out[col]);
            ebuf[(size_t)row * OO + col] = e;
            ps[r] += e;
        }
    // reduce over l15 (16 lanes); l4 bits untouched so rows stay separate
    #pragma unroll
    for (int r = 0; r < 4; ++r) {
        #pragma unroll
        for (int off = 1; off < 16; off <<= 1)
            ps[r] += __shfl_xor(ps[r], off, 64);
    }
    if (l15 == 0) {
        #pragma unroll
        for (int r = 0; r < 4; ++r) {
            int row = b0 + w * 16 + l4 * 4 + r;
            Spart[(size_t)row * 16 + ot] = ps[r];
        }
    }
}

// ---------------------------------------------------------------------------
// softmax_out: final slice (slice 0) from ebuf/Spart of step TT-1.
// ---------------------------------------------------------------------------
__global__ __launch_bounds__(256) void softmax_out(
    const float* __restrict__ ebuf, const float* __restrict__ Spart,
    float* __restrict__ out_slice)
{
    const int w = threadIdx.x >> 6, l = threadIdx.x & 63;
    const int b = blockIdx.x * 4 + w;
    const float* sp = &Spart[(size_t)b * 16];
    float s = 0.f;
    #pragma unroll
    for (int u = 0; u < 16; ++u) s += sp[u];
    float inv = 1.f / s;
    float v[8], y[8];
    *(float4*)&v[0] = *(const float4*)&ebuf[(size_t)b * OO + l * 8];
    *(float4*)&v[4] = *(const float4*)&ebuf[(size_t)b * OO + l * 8 + 4];
    #pragma unroll
    for (int u = 0; u < 8; ++u) y[u] = v[u] * inv;
    *(float4*)&out_slice[(size_t)b * OO + l * 8]     = *(const float4*)&y[0];
    *(float4*)&out_slice[(size_t)b * OO + l * 8 + 4] = *(const float4*)&y[4];
}

// ---------------------------------------------------------------------------
extern "C" void kernel_launch(void* const* d_in, const int* in_sizes, int n_in,
                              void* d_out, int out_size, void* d_ws, size_t ws_size,
                              hipStream_t stream)
{
    const float* h0    = (const float*)d_in[0];
    const float* c0    = (const float*)d_in[1];
    const float* W_ih  = (const float*)d_in[2];
    const float* W_hh  = (const float*)d_in[3];
    const float* b_ih  = (const float*)d_in[4];
    const float* b_hh  = (const float*)d_in[5];
    const float* W_out = (const float*)d_in[6];
    const float* b_out = (const float*)d_in[7];
    float* out = (float*)d_out;

    char* wsb = (char*)d_ws;
    _Float16* Wcat   = (_Float16*)wsb;                 wsb += (size_t)G4H * KC * 2;
    _Float16* Wout16 = (_Float16*)wsb;                 wsb += (size_t)OO * HH * 2;
    float*    bias_p = (float*)wsb;                    wsb += (size_t)G4H * 4;
    _Float16* hb0    = (_Float16*)wsb;                 wsb += (size_t)BB * HH * 2;
    _Float16* hb1    = (_Float16*)wsb;                 wsb += (size_t)BB * HH * 2;
    float*    cst    = (float*)wsb;                    wsb += (size_t)BB * HH * 4;
    float*    ebuf   = (float*)wsb;                    wsb += (size_t)BB * OO * 4;
    float*    Spart  = (float*)wsb;                    wsb += (size_t)BB * 16 * 4;

    conv_wcat<<<dim3(KC / 256, G4H), 256, 0, stream>>>(W_ih, W_hh, Wcat);
    conv_wout<<<dim3(HH / 256, OO), 256, 0, stream>>>(W_out, Wout16);
    prep_misc<<<512, 256, 0, stream>>>(b_ih, b_hh, h0, c0, bias_p, hb0, cst);

    for (int t = 0; t < TT; ++t) {
        _Float16* hin  = (t & 1) ? hb1 : hb0;
        _Float16* hout = (t & 1) ? hb0 : hb1;
        // gates_sf2 at step t consumes y_{t-1} = e/S inline (x never
        // materialized) and writes the out slice for step t-1 (slice TT-t).
        float* oslice = (t == 0) ? out : out + (size_t)(TT - t) * BB * OO;
        gates_sf2<<<dim3(32, 8), 256, 0, stream>>>(
            ebuf, Spart, hin, hout, cst, Wcat, bias_p, oslice, (t == 0) ? 1 : 0);
        logits_exp<<<dim3(16, 16), 128, 0, stream>>>(hout, Wout16, b_out, ebuf, Spart);
    }
    // final: slice 0 from ebuf/Spart of step TT-1
    softmax_out<<<128, 256, 0, stream>>>(ebuf, Spart, out);
}